// Round 1
// baseline (511.917 us; speedup 1.0000x reference)
//
#include <hip/hip_runtime.h>
#include <stdint.h>
#include <stddef.h>

#define NN 1000000
#define KT 9
#define NEG_SLOPE 0.01f
#define BN_EPS 1e-5f

typedef float f32x4 __attribute__((ext_vector_type(4)));
typedef short bf16x8 __attribute__((ext_vector_type(8)));

__device__ __forceinline__ short f2bf(float f) {
    union { float f; uint32_t u; } x; x.f = f;
    uint32_t u = x.u;
    uint32_t r = (u + 0x7FFFu + ((u >> 16) & 1u)) >> 16;   // RNE
    return (short)(r & 0xFFFFu);
}

// ws layout (floats): [0..31] sum[c], [32..63] sumsq[c], [64..95] scale[c],
// [96..127] shift[c], [128] mask-mode flag (int: 0=u8, 1=i32, 2=f32)

__global__ void detect_mask_mode_kernel(const uint32_t* __restrict__ mask,
                                        int* __restrict__ flag) {
    if (blockIdx.x == 0 && threadIdx.x == 0) {
        bool anyf = false, anybig = false;
        for (int i = 0; i < 256; ++i) {
            uint32_t w = mask[i];
            if (w == 0x3F800000u) anyf = true;
            else if (w > 1u) anybig = true;
        }
        *flag = anyf ? 2 : (anybig ? 0 : 1);
    }
}

__global__ __launch_bounds__(256) void spconv_kernel(
    const float* __restrict__ feat, const float* __restrict__ wgt,
    const int* __restrict__ nidx, const void* __restrict__ nmask,
    const int* __restrict__ flag, float* __restrict__ out,
    float* __restrict__ stats)
{
    const int mode = *flag;
    const int lane = threadIdx.x & 63;
    const int w    = threadIdx.x >> 6;
    const int col  = lane & 15;          // output channel (low half) / voxel-in-tile
    const int kg   = lane >> 4;          // k-group 0..3
    const int k0   = kg * 8;             // first k (=ci) element this lane holds

    // B fragments: wb[k][h] component j = W[k][k0+j][h*16+col]
    bf16x8 wb[KT][2];
    #pragma unroll
    for (int k = 0; k < KT; ++k) {
        #pragma unroll
        for (int h = 0; h < 2; ++h) {
            bf16x8 b;
            #pragma unroll
            for (int j = 0; j < 8; ++j)
                b[j] = f2bf(wgt[k * 1024 + (k0 + j) * 32 + h * 16 + col]);
            wb[k][h] = b;
        }
    }

    float s0 = 0.f, s1 = 0.f, q0 = 0.f, q1 = 0.f;

    const int gwave = blockIdx.x * 4 + w;
    const int nwave = gridDim.x * 4;
    const int NT = NN / 16;
    const uint8_t* m8  = (const uint8_t*)nmask;
    const int*     m32 = (const int*)nmask;
    const float*   mf  = (const float*)nmask;

    for (int t = gwave; t < NT; t += nwave) {
        const int vbase = t * 16;
        const int v = vbase + col;       // this lane's voxel (per A-row)
        f32x4 acc0 = {0.f, 0.f, 0.f, 0.f};
        f32x4 acc1 = {0.f, 0.f, 0.f, 0.f};
        #pragma unroll
        for (int k = 0; k < KT; ++k) {
            const int e = k * NN + v;
            bool act;
            if (mode == 0)      act = (m8[e]  != 0);
            else if (mode == 1) act = (m32[e] != 0);
            else                act = (mf[e]  != 0.0f);
            bf16x8 a = {0, 0, 0, 0, 0, 0, 0, 0};
            if (act) {
                const int id = nidx[e];
                const float* src = feat + (size_t)id * 32 + k0;
                const f32x4 lo = *(const f32x4*)(src);
                const f32x4 hi = *(const f32x4*)(src + 4);
                #pragma unroll
                for (int j = 0; j < 4; ++j) { a[j] = f2bf(lo[j]); a[j + 4] = f2bf(hi[j]); }
            }
            acc0 = __builtin_amdgcn_mfma_f32_16x16x32_bf16(a, wb[k][0], acc0, 0, 0, 0);
            acc1 = __builtin_amdgcn_mfma_f32_16x16x32_bf16(a, wb[k][1], acc1, 0, 0, 0);
        }
        // Epilogue: D layout col=lane&15, row=(lane>>4)*4+reg (m89-verified)
        #pragma unroll
        for (int r = 0; r < 4; ++r) {
            const int row = vbase + kg * 4 + r;
            float y0 = acc0[r]; y0 = (y0 >= 0.f) ? y0 : NEG_SLOPE * y0;
            float y1 = acc1[r]; y1 = (y1 >= 0.f) ? y1 : NEG_SLOPE * y1;
            out[row * 32 + col]      = y0;
            out[row * 32 + 16 + col] = y1;
            s0 += y0; q0 += y0 * y0;
            s1 += y1; q1 += y1 * y1;
        }
    }

    // reduce across the 4 lanes that share `col` (l, l^16, l^32, l^48)
    s0 += __shfl_xor(s0, 16); s0 += __shfl_xor(s0, 32);
    s1 += __shfl_xor(s1, 16); s1 += __shfl_xor(s1, 32);
    q0 += __shfl_xor(q0, 16); q0 += __shfl_xor(q0, 32);
    q1 += __shfl_xor(q1, 16); q1 += __shfl_xor(q1, 32);

    __shared__ float red[4][64];
    if (lane < 16) {
        red[w][col]      = s0;  red[w][col + 16] = s1;
        red[w][col + 32] = q0;  red[w][col + 48] = q1;
    }
    __syncthreads();
    if (threadIdx.x < 64) {
        float tot = red[0][threadIdx.x] + red[1][threadIdx.x]
                  + red[2][threadIdx.x] + red[3][threadIdx.x];
        atomicAdd(&stats[threadIdx.x], tot);
    }
}

__global__ void bn_stats_kernel(const float* __restrict__ stats,
                                const float* __restrict__ gamma,
                                const float* __restrict__ beta,
                                float* __restrict__ sc) {
    int c = threadIdx.x;
    if (c < 32) {
        const float inv_n = 1.0f / (float)NN;
        float mean = stats[c] * inv_n;
        float var  = stats[32 + c] * inv_n - mean * mean;
        float s    = gamma[c] * rsqrtf(var + BN_EPS);
        sc[c]      = s;
        sc[32 + c] = beta[c] - mean * s;
    }
}

__global__ __launch_bounds__(256) void bn_apply_kernel(float* __restrict__ out,
                                                       const float* __restrict__ sc) {
    __shared__ float s[32], b[32];
    if (threadIdx.x < 32)      s[threadIdx.x] = sc[threadIdx.x];
    else if (threadIdx.x < 64) b[threadIdx.x - 32] = sc[threadIdx.x];
    __syncthreads();
    f32x4* o4 = (f32x4*)out;
    const int total4 = NN * 32 / 4;
    for (int i = blockIdx.x * blockDim.x + threadIdx.x; i < total4;
         i += gridDim.x * blockDim.x) {
        f32x4 v = o4[i];
        const int c0 = (i & 7) * 4;
        v[0] = v[0] * s[c0]     + b[c0];
        v[1] = v[1] * s[c0 + 1] + b[c0 + 1];
        v[2] = v[2] * s[c0 + 2] + b[c0 + 2];
        v[3] = v[3] * s[c0 + 3] + b[c0 + 3];
        o4[i] = v;
    }
}

extern "C" void kernel_launch(void* const* d_in, const int* in_sizes, int n_in,
                              void* d_out, int out_size, void* d_ws, size_t ws_size,
                              hipStream_t stream) {
    const float* feat  = (const float*)d_in[0];
    const float* wgt   = (const float*)d_in[1];
    const float* gamma = (const float*)d_in[2];
    const float* beta  = (const float*)d_in[3];
    const int*   nidx  = (const int*)d_in[4];
    const void*  nmask = d_in[5];
    float* out = (float*)d_out;
    float* ws  = (float*)d_ws;

    hipMemsetAsync(ws, 0, 64 * sizeof(float), stream);   // zero stats accumulators
    detect_mask_mode_kernel<<<1, 64, 0, stream>>>((const uint32_t*)nmask,
                                                  (int*)(ws + 128));
    spconv_kernel<<<1024, 256, 0, stream>>>(feat, wgt, nidx, nmask,
                                            (const int*)(ws + 128), out, ws);
    bn_stats_kernel<<<1, 64, 0, stream>>>(ws, gamma, beta, ws + 64);
    bn_apply_kernel<<<2048, 256, 0, stream>>>(out, ws + 64);
}